// Round 1
// baseline (368.935 us; speedup 1.0000x reference)
//
#include <hip/hip_runtime.h>
#include <hip/hip_bf16.h>

typedef __attribute__((ext_vector_type(8))) short short8;
typedef __attribute__((ext_vector_type(4))) float f32x4;

constexpr int B_ = 4, S_ = 2048, D_ = 512, H_ = 8, DP_ = 64;
constexpr int M_ = B_ * S_;  // 8192 rows

__device__ __forceinline__ unsigned short f2b(float f) {
    __hip_bfloat16 h = __float2bfloat16(f);
    return *reinterpret_cast<unsigned short*>(&h);
}

#define MFMA16(a, b, c) __builtin_amdgcn_mfma_f32_16x16x32_bf16((a), (b), (c), 0, 0, 0)

// ---------------- fp32 -> bf16 convert (x) ----------------
__global__ __launch_bounds__(256)
void convert_x(const float* __restrict__ in, unsigned short* __restrict__ out) {
    int i = blockIdx.x * 256 + threadIdx.x;   // one float4 per thread
    float4 v = ((const float4*)in)[i];
    ushort4 o;
    o.x = f2b(v.x); o.y = f2b(v.y); o.z = f2b(v.z); o.w = f2b(v.w);
    ((ushort4*)out)[i] = o;
}

// ---------------- weight transpose + convert: Wt[n][k] = bf16(W[k][n]) ----------------
__global__ __launch_bounds__(256)
void transpose_w(const float* __restrict__ w0, const float* __restrict__ w1,
                 const float* __restrict__ w2, const float* __restrict__ w3,
                 unsigned short* __restrict__ outw) {
    const float* in = (blockIdx.z == 0) ? w0 : (blockIdx.z == 1) ? w1
                     : (blockIdx.z == 2) ? w2 : w3;
    unsigned short* out = outw + (size_t)blockIdx.z * D_ * D_;
    __shared__ float t[64][65];
    int k0 = blockIdx.x * 64, n0 = blockIdx.y * 64;
    int tx = threadIdx.x & 63, ty = threadIdx.x >> 6;
#pragma unroll
    for (int i = 0; i < 16; i++) {
        int r = ty * 16 + i;
        t[r][tx] = in[(size_t)(k0 + r) * D_ + n0 + tx];
    }
    __syncthreads();
#pragma unroll
    for (int i = 0; i < 16; i++) {
        int r = ty * 16 + i;
        out[(size_t)(n0 + r) * D_ + k0 + tx] = f2b(t[tx][r]);
    }
}

// ---------------- QKV GEMM (Q,K only): [8192x512] @ W -> scatter to [B][H][S][64] ----------------
__global__ __launch_bounds__(256, 2)
void gemm_qkv(const unsigned short* __restrict__ X,
              const unsigned short* __restrict__ Wt,   // [2][512][512] transposed bf16
              unsigned short* __restrict__ QKV) {      // [2][B][H][S][64]
    const unsigned short* Bt = Wt + (size_t)blockIdx.z * D_ * D_;
    unsigned short* out = QKV + (size_t)blockIdx.z * M_ * D_;
    int m0 = blockIdx.x * 128, n0 = blockIdx.y * 128;
    int tid = threadIdx.x;
    int wave = tid >> 6, lane = tid & 63, l16 = lane & 15, quad = lane >> 4;
    int wm = (wave >> 1) * 64, wn = (wave & 1) * 64;

    __shared__ __align__(16) unsigned short As[128][40];
    __shared__ __align__(16) unsigned short Bs[128][40];

    f32x4 acc[4][4];
    const f32x4 zf = {0.f, 0.f, 0.f, 0.f};
#pragma unroll
    for (int i = 0; i < 4; i++)
#pragma unroll
        for (int j = 0; j < 4; j++) acc[i][j] = zf;

    for (int k0 = 0; k0 < D_; k0 += 32) {
        __syncthreads();
#pragma unroll
        for (int i = 0; i < 2; i++) {
            int c = tid + i * 256;
            int row = c >> 2, off = (c & 3) * 8;
            *(short8*)&As[row][off] = *(const short8*)(X + (size_t)(m0 + row) * D_ + k0 + off);
            *(short8*)&Bs[row][off] = *(const short8*)(Bt + (size_t)(n0 + row) * D_ + k0 + off);
        }
        __syncthreads();
        short8 af[4], bf[4];
#pragma unroll
        for (int mt = 0; mt < 4; mt++) af[mt] = *(const short8*)&As[wm + mt * 16 + l16][quad * 8];
#pragma unroll
        for (int nt = 0; nt < 4; nt++) bf[nt] = *(const short8*)&Bs[wn + nt * 16 + l16][quad * 8];
#pragma unroll
        for (int mt = 0; mt < 4; mt++)
#pragma unroll
            for (int nt = 0; nt < 4; nt++)
                acc[mt][nt] = MFMA16(af[mt], bf[nt], acc[mt][nt]);
    }
    // epilogue: C/D layout col=lane&15, row=quad*4+r; scatter to [B][H][S][64]
#pragma unroll
    for (int mt = 0; mt < 4; mt++)
#pragma unroll
        for (int nt = 0; nt < 4; nt++)
#pragma unroll
            for (int r = 0; r < 4; r++) {
                int m = m0 + wm + mt * 16 + quad * 4 + r;
                int n = n0 + wn + nt * 16 + l16;
                int bb = m >> 11, ss = m & 2047, hh = n >> 6, dd = n & 63;
                out[(((size_t)bb * H_ + hh) * S_ + ss) * DP_ + dd] = f2b(acc[mt][nt][r]);
            }
}

// ---------------- V^T GEMM: Vt_b = Wv^T (.) X_b^T  -> [B][512][2048] ----------------
// out[m][n] = sum_k Wv^T[m][k] * X[b*S+n][k] = V_b[n][m]  (coalesced along n=s)
__global__ __launch_bounds__(256, 2)
void gemm_vt(const unsigned short* __restrict__ X,
             const unsigned short* __restrict__ Wt,   // Wv^T [512][512] bf16
             unsigned short* __restrict__ Vt) {       // [B][D][S] bf16
    int bb = blockIdx.z;
    int m0 = blockIdx.x * 128, n0 = blockIdx.y * 128;
    int tid = threadIdx.x;
    int wave = tid >> 6, lane = tid & 63, l16 = lane & 15, quad = lane >> 4;
    int wm = (wave >> 1) * 64, wn = (wave & 1) * 64;

    __shared__ __align__(16) unsigned short As[128][40];
    __shared__ __align__(16) unsigned short Bs[128][40];

    f32x4 acc[4][4];
    const f32x4 zf = {0.f, 0.f, 0.f, 0.f};
#pragma unroll
    for (int i = 0; i < 4; i++)
#pragma unroll
        for (int j = 0; j < 4; j++) acc[i][j] = zf;

    for (int k0 = 0; k0 < D_; k0 += 32) {
        __syncthreads();
#pragma unroll
        for (int i = 0; i < 2; i++) {
            int c = tid + i * 256;
            int row = c >> 2, off = (c & 3) * 8;
            *(short8*)&As[row][off] = *(const short8*)(Wt + (size_t)(m0 + row) * D_ + k0 + off);
            *(short8*)&Bs[row][off] = *(const short8*)(X + (size_t)(bb * S_ + n0 + row) * D_ + k0 + off);
        }
        __syncthreads();
        short8 af[4], bf[4];
#pragma unroll
        for (int mt = 0; mt < 4; mt++) af[mt] = *(const short8*)&As[wm + mt * 16 + l16][quad * 8];
#pragma unroll
        for (int nt = 0; nt < 4; nt++) bf[nt] = *(const short8*)&Bs[wn + nt * 16 + l16][quad * 8];
#pragma unroll
        for (int mt = 0; mt < 4; mt++)
#pragma unroll
            for (int nt = 0; nt < 4; nt++)
                acc[mt][nt] = MFMA16(af[mt], bf[nt], acc[mt][nt]);
    }
#pragma unroll
    for (int mt = 0; mt < 4; mt++)
#pragma unroll
        for (int nt = 0; nt < 4; nt++)
#pragma unroll
            for (int r = 0; r < 4; r++) {
                int m = m0 + wm + mt * 16 + quad * 4 + r;   // d-row in [0,512)
                int n = n0 + wn + nt * 16 + l16;            // s in [0,2048)
                Vt[((size_t)bb * D_ + m) * S_ + n] = f2b(acc[mt][nt][r]);
            }
}

// ---------------- flash attention: per (b,h,64-q-rows) block, barrier-free kv loop ----------------
__global__ __launch_bounds__(256, 2)
void flash_attn(const unsigned short* __restrict__ Qg, const unsigned short* __restrict__ Kg,
                const unsigned short* __restrict__ Vt, unsigned short* __restrict__ ctx) {
    int bid = blockIdx.x;
    int qt = bid & 31, hh = (bid >> 5) & 7, bb = bid >> 8;
    int tid = threadIdx.x;
    int wave = tid >> 6, lane = tid & 63, l16 = lane & 15, quad = lane >> 4;

    size_t bh = ((size_t)bb * H_ + hh) * S_ * DP_;
    const unsigned short* Qb = Qg + bh;
    const unsigned short* Kb = Kg + bh;
    const unsigned short* Vb = Vt + bh;   // V^T: 64 rows (d), 2048 cols (s)

    // per-wave P staging, XOR-swizzled: element (row,col) lives at col ^ ((row>>2)<<4)
    // write banks: (nt*8 + l16>>1) ^ (quad<<3) -> 32 distinct, 2-way (free)
    // read (b128, row=l16) stays 16B-aligned and bank-balanced
    __shared__ __align__(16) unsigned short Ps[4][16][128];

    // Q A-fragments held in registers for the whole kernel (K=64 -> 2 frags)
    short8 qf0, qf1;
    {
        const unsigned short* qp = Qb + (size_t)(qt * 64 + wave * 16 + l16) * DP_ + quad * 8;
        qf0 = *(const short8*)qp;
        qf1 = *(const short8*)(qp + 32);
    }

    const f32x4 zf = {0.f, 0.f, 0.f, 0.f};
    f32x4 oacc[4];
#pragma unroll
    for (int i = 0; i < 4; i++) oacc[i] = zf;
    float mrow[4], lrow[4];
#pragma unroll
    for (int r = 0; r < 4; r++) { mrow[r] = -1e30f; lrow[r] = 0.f; }
    constexpr float scale = 0.125f;  // 1/sqrt(64)

    const int wsw = quad << 4;        // write swizzle (row = quad*4+r -> row>>2 == quad)
    const int rsw = (l16 >> 2) << 4;  // read swizzle  (row = l16)

    for (int kv = 0; kv < S_; kv += 128) {
        // S = Q K^T : wave's 16 q-rows x 128 keys; K B-frags direct from global (L2-hot)
        f32x4 sacc[8];
#pragma unroll
        for (int nt = 0; nt < 8; nt++) {
            const unsigned short* kp = Kb + (size_t)(kv + nt * 16 + l16) * DP_ + quad * 8;
            short8 kf0 = *(const short8*)kp;
            short8 kf1 = *(const short8*)(kp + 32);
            f32x4 s = zf;
            s = MFMA16(qf0, kf0, s);
            s = MFMA16(qf1, kf1, s);
            sacc[nt] = s;
        }
        // online softmax (q-row = quad*4+r; 16 lanes sharing quad span the 128 cols)
        float alpha[4];
#pragma unroll
        for (int r = 0; r < 4; r++) {
            float mx = sacc[0][r];
#pragma unroll
            for (int nt = 1; nt < 8; nt++) mx = fmaxf(mx, sacc[nt][r]);
            mx *= scale;
#pragma unroll
            for (int off = 1; off < 16; off <<= 1) mx = fmaxf(mx, __shfl_xor(mx, off));
            float mn = fmaxf(mrow[r], mx);
            alpha[r] = __expf(mrow[r] - mn);
            mrow[r] = mn;
        }
        float rs[4] = {0.f, 0.f, 0.f, 0.f};
#pragma unroll
        for (int nt = 0; nt < 8; nt++)
#pragma unroll
            for (int r = 0; r < 4; r++) {
                float p = __expf(sacc[nt][r] * scale - mrow[r]);
                rs[r] += p;
                Ps[wave][quad * 4 + r][(nt * 16 + l16) ^ wsw] = f2b(p);
            }
#pragma unroll
        for (int r = 0; r < 4; r++) {
            float s = rs[r];
#pragma unroll
            for (int off = 1; off < 16; off <<= 1) s += __shfl_xor(s, off);
            lrow[r] = alpha[r] * lrow[r] + s;
        }
#pragma unroll
        for (int ot = 0; ot < 4; ot++)
#pragma unroll
            for (int r = 0; r < 4; r++) oacc[ot][r] *= alpha[r];
        // O += P V : P via per-wave LDS layout-change; V^T B-frags direct from global (L2-hot)
#pragma unroll
        for (int kt = 0; kt < 4; kt++) {
            short8 pf = *(const short8*)&Ps[wave][l16][(kt * 32 + quad * 8) ^ rsw];
#pragma unroll
            for (int ot = 0; ot < 4; ot++) {
                short8 vf = *(const short8*)(Vb + (size_t)(ot * 16 + l16) * S_ + kv + kt * 32 + quad * 8);
                oacc[ot] = MFMA16(pf, vf, oacc[ot]);
            }
        }
    }
    // epilogue: normalize, merge heads into [B][S][512]
#pragma unroll
    for (int ot = 0; ot < 4; ot++)
#pragma unroll
        for (int r = 0; r < 4; r++) {
            float o = oacc[ot][r] / lrow[r];
            int srow = qt * 64 + wave * 16 + quad * 4 + r;
            ctx[((size_t)bb * S_ + srow) * D_ + hh * DP_ + ot * 16 + l16] = f2b(o);
        }
}

// ---------------- output projection GEMM -> fp32 scratch ----------------
__global__ __launch_bounds__(256, 2)
void gemm_proj(const unsigned short* __restrict__ A,   // ctx [8192][512] bf16
               const unsigned short* __restrict__ Bt,  // Wo^T [512][512] bf16
               float* __restrict__ outf) {             // [8192][512] fp32
    int m0 = blockIdx.x * 128, n0 = blockIdx.y * 128;
    int tid = threadIdx.x;
    int wave = tid >> 6, lane = tid & 63, l16 = lane & 15, quad = lane >> 4;
    int wm = (wave >> 1) * 64, wn = (wave & 1) * 64;

    __shared__ __align__(16) unsigned short As[128][40];
    __shared__ __align__(16) unsigned short Bs[128][40];

    f32x4 acc[4][4];
    const f32x4 zf = {0.f, 0.f, 0.f, 0.f};
#pragma unroll
    for (int i = 0; i < 4; i++)
#pragma unroll
        for (int j = 0; j < 4; j++) acc[i][j] = zf;

    for (int k0 = 0; k0 < D_; k0 += 32) {
        __syncthreads();
#pragma unroll
        for (int i = 0; i < 2; i++) {
            int c = tid + i * 256;
            int row = c >> 2, off = (c & 3) * 8;
            *(short8*)&As[row][off] = *(const short8*)(A + (size_t)(m0 + row) * D_ + k0 + off);
            *(short8*)&Bs[row][off] = *(const short8*)(Bt + (size_t)(n0 + row) * D_ + k0 + off);
        }
        __syncthreads();
        short8 af[4], bf[4];
#pragma unroll
        for (int mt = 0; mt < 4; mt++) af[mt] = *(const short8*)&As[wm + mt * 16 + l16][quad * 8];
#pragma unroll
        for (int nt = 0; nt < 4; nt++) bf[nt] = *(const short8*)&Bs[wn + nt * 16 + l16][quad * 8];
#pragma unroll
        for (int mt = 0; mt < 4; mt++)
#pragma unroll
            for (int nt = 0; nt < 4; nt++)
                acc[mt][nt] = MFMA16(af[mt], bf[nt], acc[mt][nt]);
    }
#pragma unroll
    for (int mt = 0; mt < 4; mt++)
#pragma unroll
        for (int nt = 0; nt < 4; nt++)
#pragma unroll
            for (int r = 0; r < 4; r++) {
                int m = m0 + wm + mt * 16 + quad * 4 + r;
                int n = n0 + wn + nt * 16 + l16;
                outf[(size_t)m * D_ + n] = acc[mt][nt][r];
            }
}

// ---------------- bias + residual + LayerNorm (all fp32), one block per row ----------------
__global__ __launch_bounds__(256, 4)
void ln_out(const float* __restrict__ tmp, const float* __restrict__ Xg,
            const float* __restrict__ bo, const float* __restrict__ gamma,
            const float* __restrict__ beta, float* __restrict__ outp) {
    int row = blockIdx.x;
    int tid = threadIdx.x;
    int lane = tid & 63, wave = tid >> 6;
    float resid[2];
#pragma unroll
    for (int i = 0; i < 2; i++) {
        int c = tid + i * 256;
        resid[i] = Xg[(size_t)row * D_ + c] + tmp[(size_t)row * D_ + c] + bo[c];
    }
    float sum = resid[0] + resid[1];
    float sq = resid[0] * resid[0] + resid[1] * resid[1];
#pragma unroll
    for (int off = 1; off < 64; off <<= 1) {
        sum += __shfl_xor(sum, off);
        sq += __shfl_xor(sq, off);
    }
    __shared__ float red[8];
    if (lane == 0) { red[wave] = sum; red[4 + wave] = sq; }
    __syncthreads();
    sum = red[0] + red[1] + red[2] + red[3];
    sq = red[4] + red[5] + red[6] + red[7];
    float mu = sum * (1.0f / D_);
    float var = sq * (1.0f / D_) - mu * mu;
    float rstd = rsqrtf(var + 1e-6f);
#pragma unroll
    for (int i = 0; i < 2; i++) {
        int c = tid + i * 256;
        float o = (resid[i] - mu) * rstd * gamma[c] + beta[c];
        outp[(size_t)row * D_ + c] = o;
    }
}

extern "C" void kernel_launch(void* const* d_in, const int* in_sizes, int n_in,
                              void* d_out, int out_size, void* d_ws, size_t ws_size,
                              hipStream_t stream) {
    const float* x     = (const float*)d_in[0];
    const float* wq    = (const float*)d_in[1];
    const float* wk    = (const float*)d_in[2];
    const float* wv    = (const float*)d_in[3];
    const float* wo    = (const float*)d_in[4];
    const float* bo    = (const float*)d_in[5];
    const float* gamma = (const float*)d_in[6];
    const float* beta  = (const float*)d_in[7];
    float* out = (float*)d_out;

    // ws layout (bf16 elems unless noted), total 34 MB:
    //   [xb 8MB | wt 2MB | Q,K,Vt 24MB]
    //   ctx aliases xb (xb dead after the projection GEMMs). fp32 tmp aliases Q (dead after flash).
    unsigned short* xb  = (unsigned short*)d_ws;                    // 8192*512 bf16
    unsigned short* wt  = xb + (size_t)M_ * D_;                     // 4*512*512 bf16
    unsigned short* Q   = wt + 4 * D_ * D_;
    unsigned short* K   = Q + (size_t)M_ * D_;
    unsigned short* Vt  = K + (size_t)M_ * D_;                      // [B][512][2048]
    unsigned short* ctx = xb;                                       // alias: xb dead
    float* tmp = (float*)Q;                                         // alias: Q/K/Vt dead

    convert_x<<<dim3(M_ * D_ / 4 / 256), 256, 0, stream>>>(x, xb);
    transpose_w<<<dim3(8, 8, 4), 256, 0, stream>>>(wq, wk, wv, wo, wt);
    gemm_qkv<<<dim3(64, 4, 2), 256, 0, stream>>>(xb, wt, Q);
    gemm_vt<<<dim3(4, 16, 4), 256, 0, stream>>>(xb, wt + 2 * (size_t)D_ * D_, Vt);
    flash_attn<<<dim3(1024), 256, 0, stream>>>(Q, K, Vt, ctx);
    gemm_proj<<<dim3(64, 4), 256, 0, stream>>>(ctx, wt + 3 * (size_t)D_ * D_, tmp);
    ln_out<<<dim3(8192), 256, 0, stream>>>(tmp, x, bo, gamma, beta, out);
}

// Round 2
// 271.098 us; speedup vs baseline: 1.3609x; 1.3609x over previous
//
#include <hip/hip_runtime.h>
#include <hip/hip_bf16.h>

typedef __attribute__((ext_vector_type(8))) short short8;
typedef __attribute__((ext_vector_type(4))) float f32x4;

constexpr int B_ = 4, S_ = 2048, D_ = 512, H_ = 8, DP_ = 64;
constexpr int M_ = B_ * S_;  // 8192 rows

__device__ __forceinline__ unsigned short f2b(float f) {
    __hip_bfloat16 h = __float2bfloat16(f);
    return *reinterpret_cast<unsigned short*>(&h);
}

#define MFMA16(a, b, c) __builtin_amdgcn_mfma_f32_16x16x32_bf16((a), (b), (c), 0, 0, 0)

// ---------------- fp32 -> bf16 convert (x) ----------------
__global__ __launch_bounds__(256)
void convert_x(const float* __restrict__ in, unsigned short* __restrict__ out) {
    int i = blockIdx.x * 256 + threadIdx.x;   // one float4 per thread
    float4 v = ((const float4*)in)[i];
    ushort4 o;
    o.x = f2b(v.x); o.y = f2b(v.y); o.z = f2b(v.z); o.w = f2b(v.w);
    ((ushort4*)out)[i] = o;
}

// ---------------- weight transpose + convert: Wt[n][k] = bf16(W[k][n]) ----------------
__global__ __launch_bounds__(256)
void transpose_w(const float* __restrict__ w0, const float* __restrict__ w1,
                 const float* __restrict__ w2, const float* __restrict__ w3,
                 unsigned short* __restrict__ outw) {
    const float* in = (blockIdx.z == 0) ? w0 : (blockIdx.z == 1) ? w1
                     : (blockIdx.z == 2) ? w2 : w3;
    unsigned short* out = outw + (size_t)blockIdx.z * D_ * D_;
    __shared__ float t[64][65];
    int k0 = blockIdx.x * 64, n0 = blockIdx.y * 64;
    int tx = threadIdx.x & 63, ty = threadIdx.x >> 6;
#pragma unroll
    for (int i = 0; i < 16; i++) {
        int r = ty * 16 + i;
        t[r][tx] = in[(size_t)(k0 + r) * D_ + n0 + tx];
    }
    __syncthreads();
#pragma unroll
    for (int i = 0; i < 16; i++) {
        int r = ty * 16 + i;
        out[(size_t)(n0 + r) * D_ + k0 + tx] = f2b(t[tx][r]);
    }
}

// ---------------- QKV GEMM (Q,K only): [8192x512] @ W -> scatter to [B][H][S][64] ----------------
__global__ __launch_bounds__(256, 2)
void gemm_qkv(const unsigned short* __restrict__ X,
              const unsigned short* __restrict__ Wt,   // [2][512][512] transposed bf16
              unsigned short* __restrict__ QKV) {      // [2][B][H][S][64]
    const unsigned short* Bt = Wt + (size_t)blockIdx.z * D_ * D_;
    unsigned short* out = QKV + (size_t)blockIdx.z * M_ * D_;
    int m0 = blockIdx.x * 128, n0 = blockIdx.y * 128;
    int tid = threadIdx.x;
    int wave = tid >> 6, lane = tid & 63, l16 = lane & 15, quad = lane >> 4;
    int wm = (wave >> 1) * 64, wn = (wave & 1) * 64;

    __shared__ __align__(16) unsigned short As[128][40];
    __shared__ __align__(16) unsigned short Bs[128][40];

    f32x4 acc[4][4];
    const f32x4 zf = {0.f, 0.f, 0.f, 0.f};
#pragma unroll
    for (int i = 0; i < 4; i++)
#pragma unroll
        for (int j = 0; j < 4; j++) acc[i][j] = zf;

    for (int k0 = 0; k0 < D_; k0 += 32) {
        __syncthreads();
#pragma unroll
        for (int i = 0; i < 2; i++) {
            int c = tid + i * 256;
            int row = c >> 2, off = (c & 3) * 8;
            *(short8*)&As[row][off] = *(const short8*)(X + (size_t)(m0 + row) * D_ + k0 + off);
            *(short8*)&Bs[row][off] = *(const short8*)(Bt + (size_t)(n0 + row) * D_ + k0 + off);
        }
        __syncthreads();
        short8 af[4], bf[4];
#pragma unroll
        for (int mt = 0; mt < 4; mt++) af[mt] = *(const short8*)&As[wm + mt * 16 + l16][quad * 8];
#pragma unroll
        for (int nt = 0; nt < 4; nt++) bf[nt] = *(const short8*)&Bs[wn + nt * 16 + l16][quad * 8];
#pragma unroll
        for (int mt = 0; mt < 4; mt++)
#pragma unroll
            for (int nt = 0; nt < 4; nt++)
                acc[mt][nt] = MFMA16(af[mt], bf[nt], acc[mt][nt]);
    }
    // epilogue: C/D layout col=lane&15, row=quad*4+r; scatter to [B][H][S][64]
#pragma unroll
    for (int mt = 0; mt < 4; mt++)
#pragma unroll
        for (int nt = 0; nt < 4; nt++)
#pragma unroll
            for (int r = 0; r < 4; r++) {
                int m = m0 + wm + mt * 16 + quad * 4 + r;
                int n = n0 + wn + nt * 16 + l16;
                int bb = m >> 11, ss = m & 2047, hh = n >> 6, dd = n & 63;
                out[(((size_t)bb * H_ + hh) * S_ + ss) * DP_ + dd] = f2b(acc[mt][nt][r]);
            }
}

// ---------------- V^T GEMM: Vt_b = Wv^T (.) X_b^T  -> [B][512][2048] ----------------
// out[m][n] = sum_k Wv^T[m][k] * X[b*S+n][k] = V_b[n][m]  (coalesced along n=s)
__global__ __launch_bounds__(256, 2)
void gemm_vt(const unsigned short* __restrict__ X,
             const unsigned short* __restrict__ Wt,   // Wv^T [512][512] bf16
             unsigned short* __restrict__ Vt) {       // [B][D][S] bf16
    int bb = blockIdx.z;
    int m0 = blockIdx.x * 128, n0 = blockIdx.y * 128;
    int tid = threadIdx.x;
    int wave = tid >> 6, lane = tid & 63, l16 = lane & 15, quad = lane >> 4;
    int wm = (wave >> 1) * 64, wn = (wave & 1) * 64;

    __shared__ __align__(16) unsigned short As[128][40];
    __shared__ __align__(16) unsigned short Bs[128][40];

    f32x4 acc[4][4];
    const f32x4 zf = {0.f, 0.f, 0.f, 0.f};
#pragma unroll
    for (int i = 0; i < 4; i++)
#pragma unroll
        for (int j = 0; j < 4; j++) acc[i][j] = zf;

    for (int k0 = 0; k0 < D_; k0 += 32) {
        __syncthreads();
#pragma unroll
        for (int i = 0; i < 2; i++) {
            int c = tid + i * 256;
            int row = c >> 2, off = (c & 3) * 8;
            *(short8*)&As[row][off] = *(const short8*)(Wt + (size_t)(m0 + row) * D_ + k0 + off);
            *(short8*)&Bs[row][off] = *(const short8*)(X + (size_t)(bb * S_ + n0 + row) * D_ + k0 + off);
        }
        __syncthreads();
        short8 af[4], bf[4];
#pragma unroll
        for (int mt = 0; mt < 4; mt++) af[mt] = *(const short8*)&As[wm + mt * 16 + l16][quad * 8];
#pragma unroll
        for (int nt = 0; nt < 4; nt++) bf[nt] = *(const short8*)&Bs[wn + nt * 16 + l16][quad * 8];
#pragma unroll
        for (int mt = 0; mt < 4; mt++)
#pragma unroll
            for (int nt = 0; nt < 4; nt++)
                acc[mt][nt] = MFMA16(af[mt], bf[nt], acc[mt][nt]);
    }
#pragma unroll
    for (int mt = 0; mt < 4; mt++)
#pragma unroll
        for (int nt = 0; nt < 4; nt++)
#pragma unroll
            for (int r = 0; r < 4; r++) {
                int m = m0 + wm + mt * 16 + quad * 4 + r;   // d-row in [0,512)
                int n = n0 + wn + nt * 16 + l16;            // s in [0,2048)
                Vt[((size_t)bb * D_ + m) * S_ + n] = f2b(acc[mt][nt][r]);
            }
}

// ---------------- flash attention: per (b,h,64-q-rows) block ----------------
// V^T tile staged to LDS via coalesced vector copy (transpose-free thanks to gemm_vt);
// staging loads issued BEFORE QK^T so latency hides under MFMA (async-STAGE split).
__global__ __launch_bounds__(256, 4)
void flash_attn(const unsigned short* __restrict__ Qg, const unsigned short* __restrict__ Kg,
                const unsigned short* __restrict__ Vt, unsigned short* __restrict__ ctx) {
    int bid = blockIdx.x;
    int qt = bid & 31, hh = (bid >> 5) & 7, bb = bid >> 8;
    int tid = threadIdx.x;
    int wave = tid >> 6, lane = tid & 63, l16 = lane & 15, quad = lane >> 4;

    size_t bh = ((size_t)bb * H_ + hh) * S_ * DP_;
    const unsigned short* Qb = Qg + bh;
    const unsigned short* Kb = Kg + bh;
    const unsigned short* Vb = Vt + bh;   // V^T head slice: 64 rows (d), 2048 cols (s)

    // V^T tile [64 d][128 s], pad 8 -> stride 68 dwords: both write (4d+4c15)%32 and
    // read (4r+16kt+4q)%32 spread into 8 groups x 8 lanes = conflict-free for b128.
    __shared__ __align__(16) unsigned short Vts[64][136];
    // per-wave P staging, XOR-swizzled: element (row,col) at col ^ ((row>>2)<<4)
    __shared__ __align__(16) unsigned short Ps[4][16][128];

    // staging decomposition: thread c (+i*256) covers d = c>>4, 16B chunk (c&15)*8
    const int sd = tid >> 4, soff = (tid & 15) * 8;

    // Q A-fragments held in registers for the whole kernel (K=64 -> 2 frags)
    short8 qf0, qf1;
    {
        const unsigned short* qp = Qb + (size_t)(qt * 64 + wave * 16 + l16) * DP_ + quad * 8;
        qf0 = *(const short8*)qp;
        qf1 = *(const short8*)(qp + 32);
    }

    const f32x4 zf = {0.f, 0.f, 0.f, 0.f};
    f32x4 oacc[4];
#pragma unroll
    for (int i = 0; i < 4; i++) oacc[i] = zf;
    float mrow[4], lrow[4];
#pragma unroll
    for (int r = 0; r < 4; r++) { mrow[r] = -1e30f; lrow[r] = 0.f; }
    constexpr float scale = 0.125f;  // 1/sqrt(64)

    const int wsw = quad << 4;        // Ps write swizzle (row = quad*4+r -> row>>2 == quad)
    const int rsw = (l16 >> 2) << 4;  // Ps read swizzle  (row = l16)

    for (int kv = 0; kv < S_; kv += 128) {
        // (1) issue V^T staging loads into registers (coalesced 256B-per-row reads)
        short8 vst[4];
#pragma unroll
        for (int i = 0; i < 4; i++)
            vst[i] = *(const short8*)(Vb + (size_t)(sd + i * 16) * S_ + kv + soff);

        // (2) S = Q K^T : wave's 16 q-rows x 128 keys; K B-frags direct from global (L2-hot)
        f32x4 sacc[8];
#pragma unroll
        for (int nt = 0; nt < 8; nt++) {
            const unsigned short* kp = Kb + (size_t)(kv + nt * 16 + l16) * DP_ + quad * 8;
            short8 kf0 = *(const short8*)kp;
            short8 kf1 = *(const short8*)(kp + 32);
            f32x4 s = zf;
            s = MFMA16(qf0, kf0, s);
            s = MFMA16(qf1, kf1, s);
            sacc[nt] = s;
        }

        // (3) all waves done reading previous Vts -> write new tile
        __syncthreads();
#pragma unroll
        for (int i = 0; i < 4; i++)
            *(short8*)&Vts[sd + i * 16][soff] = vst[i];
        __syncthreads();

        // (4) online softmax (q-row = quad*4+r; 16 lanes sharing quad span the 128 cols)
        float alpha[4];
#pragma unroll
        for (int r = 0; r < 4; r++) {
            float mx = sacc[0][r];
#pragma unroll
            for (int nt = 1; nt < 8; nt++) mx = fmaxf(mx, sacc[nt][r]);
            mx *= scale;
#pragma unroll
            for (int off = 1; off < 16; off <<= 1) mx = fmaxf(mx, __shfl_xor(mx, off));
            float mn = fmaxf(mrow[r], mx);
            alpha[r] = __expf(mrow[r] - mn);
            mrow[r] = mn;
        }
        float rs[4] = {0.f, 0.f, 0.f, 0.f};
#pragma unroll
        for (int nt = 0; nt < 8; nt++)
#pragma unroll
            for (int r = 0; r < 4; r++) {
                float p = __expf(sacc[nt][r] * scale - mrow[r]);
                rs[r] += p;
                Ps[wave][quad * 4 + r][(nt * 16 + l16) ^ wsw] = f2b(p);
            }
#pragma unroll
        for (int r = 0; r < 4; r++) {
            float s = rs[r];
#pragma unroll
            for (int off = 1; off < 16; off <<= 1) s += __shfl_xor(s, off);
            lrow[r] = alpha[r] * lrow[r] + s;
        }
#pragma unroll
        for (int ot = 0; ot < 4; ot++)
#pragma unroll
            for (int r = 0; r < 4; r++) oacc[ot][r] *= alpha[r];

        // (5) O += P V : P via per-wave LDS layout-change; V from conflict-free Vts
#pragma unroll
        for (int kt = 0; kt < 4; kt++) {
            short8 pf = *(const short8*)&Ps[wave][l16][(kt * 32 + quad * 8) ^ rsw];
#pragma unroll
            for (int ot = 0; ot < 4; ot++) {
                short8 vf = *(const short8*)&Vts[ot * 16 + l16][kt * 32 + quad * 8];
                oacc[ot] = MFMA16(pf, vf, oacc[ot]);
            }
        }
    }
    // epilogue: normalize, merge heads into [B][S][512]
#pragma unroll
    for (int ot = 0; ot < 4; ot++)
#pragma unroll
        for (int r = 0; r < 4; r++) {
            float o = oacc[ot][r] / lrow[r];
            int srow = qt * 64 + wave * 16 + quad * 4 + r;
            ctx[((size_t)bb * S_ + srow) * D_ + hh * DP_ + ot * 16 + l16] = f2b(o);
        }
}

// ---------------- output projection GEMM -> fp32 scratch ----------------
__global__ __launch_bounds__(256, 2)
void gemm_proj(const unsigned short* __restrict__ A,   // ctx [8192][512] bf16
               const unsigned short* __restrict__ Bt,  // Wo^T [512][512] bf16
               float* __restrict__ outf) {             // [8192][512] fp32
    int m0 = blockIdx.x * 128, n0 = blockIdx.y * 128;
    int tid = threadIdx.x;
    int wave = tid >> 6, lane = tid & 63, l16 = lane & 15, quad = lane >> 4;
    int wm = (wave >> 1) * 64, wn = (wave & 1) * 64;

    __shared__ __align__(16) unsigned short As[128][40];
    __shared__ __align__(16) unsigned short Bs[128][40];

    f32x4 acc[4][4];
    const f32x4 zf = {0.f, 0.f, 0.f, 0.f};
#pragma unroll
    for (int i = 0; i < 4; i++)
#pragma unroll
        for (int j = 0; j < 4; j++) acc[i][j] = zf;

    for (int k0 = 0; k0 < D_; k0 += 32) {
        __syncthreads();
#pragma unroll
        for (int i = 0; i < 2; i++) {
            int c = tid + i * 256;
            int row = c >> 2, off = (c & 3) * 8;
            *(short8*)&As[row][off] = *(const short8*)(A + (size_t)(m0 + row) * D_ + k0 + off);
            *(short8*)&Bs[row][off] = *(const short8*)(Bt + (size_t)(n0 + row) * D_ + k0 + off);
        }
        __syncthreads();
        short8 af[4], bf[4];
#pragma unroll
        for (int mt = 0; mt < 4; mt++) af[mt] = *(const short8*)&As[wm + mt * 16 + l16][quad * 8];
#pragma unroll
        for (int nt = 0; nt < 4; nt++) bf[nt] = *(const short8*)&Bs[wn + nt * 16 + l16][quad * 8];
#pragma unroll
        for (int mt = 0; mt < 4; mt++)
#pragma unroll
            for (int nt = 0; nt < 4; nt++)
                acc[mt][nt] = MFMA16(af[mt], bf[nt], acc[mt][nt]);
    }
#pragma unroll
    for (int mt = 0; mt < 4; mt++)
#pragma unroll
        for (int nt = 0; nt < 4; nt++)
#pragma unroll
            for (int r = 0; r < 4; r++) {
                int m = m0 + wm + mt * 16 + quad * 4 + r;
                int n = n0 + wn + nt * 16 + l16;
                outf[(size_t)m * D_ + n] = acc[mt][nt][r];
            }
}

// ---------------- bias + residual + LayerNorm (all fp32), one block per row ----------------
__global__ __launch_bounds__(256, 4)
void ln_out(const float* __restrict__ tmp, const float* __restrict__ Xg,
            const float* __restrict__ bo, const float* __restrict__ gamma,
            const float* __restrict__ beta, float* __restrict__ outp) {
    int row = blockIdx.x;
    int tid = threadIdx.x;
    int lane = tid & 63, wave = tid >> 6;
    float resid[2];
#pragma unroll
    for (int i = 0; i < 2; i++) {
        int c = tid + i * 256;
        resid[i] = Xg[(size_t)row * D_ + c] + tmp[(size_t)row * D_ + c] + bo[c];
    }
    float sum = resid[0] + resid[1];
    float sq = resid[0] * resid[0] + resid[1] * resid[1];
#pragma unroll
    for (int off = 1; off < 64; off <<= 1) {
        sum += __shfl_xor(sum, off);
        sq += __shfl_xor(sq, off);
    }
    __shared__ float red[8];
    if (lane == 0) { red[wave] = sum; red[4 + wave] = sq; }
    __syncthreads();
    sum = red[0] + red[1] + red[2] + red[3];
    sq = red[4] + red[5] + red[6] + red[7];
    float mu = sum * (1.0f / D_);
    float var = sq * (1.0f / D_) - mu * mu;
    float rstd = rsqrtf(var + 1e-6f);
#pragma unroll
    for (int i = 0; i < 2; i++) {
        int c = tid + i * 256;
        float o = (resid[i] - mu) * rstd * gamma[c] + beta[c];
        outp[(size_t)row * D_ + c] = o;
    }
}

extern "C" void kernel_launch(void* const* d_in, const int* in_sizes, int n_in,
                              void* d_out, int out_size, void* d_ws, size_t ws_size,
                              hipStream_t stream) {
    const float* x     = (const float*)d_in[0];
    const float* wq    = (const float*)d_in[1];
    const float* wk    = (const float*)d_in[2];
    const float* wv    = (const float*)d_in[3];
    const float* wo    = (const float*)d_in[4];
    const float* bo    = (const float*)d_in[5];
    const float* gamma = (const float*)d_in[6];
    const float* beta  = (const float*)d_in[7];
    float* out = (float*)d_out;

    // ws layout (bf16 elems unless noted), total 34 MB:
    //   [xb 8MB | wt 2MB | Q,K,Vt 24MB]
    //   ctx aliases xb (xb dead after the projection GEMMs). fp32 tmp aliases Q (dead after flash).
    unsigned short* xb  = (unsigned short*)d_ws;                    // 8192*512 bf16
    unsigned short* wt  = xb + (size_t)M_ * D_;                     // 4*512*512 bf16
    unsigned short* Q   = wt + 4 * D_ * D_;
    unsigned short* K   = Q + (size_t)M_ * D_;
    unsigned short* Vt  = K + (size_t)M_ * D_;                      // [B][512][2048]
    unsigned short* ctx = xb;                                       // alias: xb dead
    float* tmp = (float*)Q;                                         // alias: Q/K/Vt dead

    convert_x<<<dim3(M_ * D_ / 4 / 256), 256, 0, stream>>>(x, xb);
    transpose_w<<<dim3(8, 8, 4), 256, 0, stream>>>(wq, wk, wv, wo, wt);
    gemm_qkv<<<dim3(64, 4, 2), 256, 0, stream>>>(xb, wt, Q);
    gemm_vt<<<dim3(4, 16, 4), 256, 0, stream>>>(xb, wt + 2 * (size_t)D_ * D_, Vt);
    flash_attn<<<dim3(1024), 256, 0, stream>>>(Q, K, Vt, ctx);
    gemm_proj<<<dim3(64, 4), 256, 0, stream>>>(ctx, wt + 3 * (size_t)D_ * D_, tmp);
    ln_out<<<dim3(8192), 256, 0, stream>>>(tmp, x, bo, gamma, beta, out);
}